// Round 1
// baseline (61.097 us; speedup 1.0000x reference)
//
#include <hip/hip_runtime.h>
#include <cmath>

// ADF tanh moment propagation.
// Reference: 128-pt Gauss-Hermite. We use trapezoid quadrature on the
// Gaussian integral: h=0.5, nodes x=-4..4 (17 pts), weights ∝ exp(-x^2),
// normalized to sum 1. Uniform error vs the exact integral (and hence vs
// the 128-pt GH reference) is <~1e-4 for all sigma in [0,1] (pole of tanh
// at Im z = pi/2 => trapezoid error ~ e^{-2*pi*1.11/h} ≈ 2e-5; truncation
// erfc(4) ≈ 1.5e-8). Threshold is 1.52e-2 absolute => 100x+ margin.

#define NQ 17

struct QTable {
    float c[NQ];  // K*sqrt(2)*x_q, where K = 2*log2(e); arg = fma(c, std, K*mu)
    float w[NQ];  // normalized weights, sum to 1
};

#if __has_builtin(__builtin_amdgcn_exp2f)
__device__ __forceinline__ float fast_exp2(float x) { return __builtin_amdgcn_exp2f(x); }
#else
__device__ __forceinline__ float fast_exp2(float x) { return exp2f(x); }
#endif
#if __has_builtin(__builtin_amdgcn_rcpf)
__device__ __forceinline__ float fast_rcp(float x) { return __builtin_amdgcn_rcpf(x); }
#else
__device__ __forceinline__ float fast_rcp(float x) { return 1.0f / x; }
#endif
#if __has_builtin(__builtin_amdgcn_sqrtf)
__device__ __forceinline__ float fast_sqrt(float x) { return __builtin_amdgcn_sqrtf(x); }
#else
__device__ __forceinline__ float fast_sqrt(float x) { return sqrtf(x); }
#endif

// kz = 2*log2(e)*z ; tanh(z) = 1 - 2/(exp2(kz)+1)
__device__ __forceinline__ float tanh_from_scaled(float kz) {
    float e = fast_exp2(kz);
    float r = fast_rcp(e + 1.0f);
    return fmaf(-2.0f, r, 1.0f);
}

__global__ __launch_bounds__(256) void adf_tanh_kernel(
    const float* __restrict__ X, float* __restrict__ out,
    int n, int n4, int nthreads, QTable T)
{
    constexpr float K = 2.8853900817779268f;  // 2/ln(2) = 2*log2(e)
    int i = blockIdx.x * 256 + threadIdx.x;

    if (i < n4) {
        // vectorized path: 4 elements per thread, rows are 16B-aligned (n%4==0)
        float4 mu4 = ((const float4*)X)[i];
        float4 vv4 = *((const float4*)(X + n) + i);
        float mu[4] = {mu4.x, mu4.y, mu4.z, mu4.w};
        float vv[4] = {vv4.x, vv4.y, vv4.z, vv4.w};
        float s[4], a0[4], m1[4], m2[4];
#pragma unroll
        for (int j = 0; j < 4; ++j) {
            s[j]  = fast_sqrt(vv[j]);
            a0[j] = K * mu[j];
            m1[j] = 0.0f;
            m2[j] = 0.0f;
        }
#pragma unroll
        for (int q = 0; q < NQ; ++q) {
            float c = T.c[q], w = T.w[q];
#pragma unroll
            for (int j = 0; j < 4; ++j) {
                float t = tanh_from_scaled(fmaf(c, s[j], a0[j]));
                m1[j] = fmaf(w, t, m1[j]);
                m2[j] = fmaf(w * t, t, m2[j]);
            }
        }
        float4 o1, o2;
        o1.x = m1[0]; o1.y = m1[1]; o1.z = m1[2]; o1.w = m1[3];
        o2.x = fmaf(-m1[0], m1[0], m2[0]);
        o2.y = fmaf(-m1[1], m1[1], m2[1]);
        o2.z = fmaf(-m1[2], m1[2], m2[2]);
        o2.w = fmaf(-m1[3], m1[3], m2[3]);
        ((float4*)out)[i] = o1;
        *((float4*)(out + n) + i) = o2;
    } else if (i < nthreads) {
        // scalar tail (n % 4 leftovers, or whole array if rows not 16B-aligned)
        int e = 4 * n4 + (i - n4);
        float mu = X[e];
        float vv = X[n + e];
        float s = fast_sqrt(vv);
        float a0 = K * mu;
        float m1 = 0.0f, m2 = 0.0f;
#pragma unroll
        for (int q = 0; q < NQ; ++q) {
            float t = tanh_from_scaled(fmaf(T.c[q], s, a0));
            m1 = fmaf(T.w[q], t, m1);
            m2 = fmaf(T.w[q] * t, t, m2);
        }
        out[e] = m1;
        out[n + e] = fmaf(-m1, m1, m2);
    }
}

static QTable make_table() {
    QTable t;
    const double h = 0.5;
    const double K = 2.0 / std::log(2.0);     // 2*log2(e)
    const double s2 = std::sqrt(2.0);
    double wraw[NQ];
    double wsum = 0.0;
    for (int q = 0; q < NQ; ++q) {
        double x = h * (double)(q - (NQ - 1) / 2);  // -4.0 .. 4.0
        wraw[q] = std::exp(-x * x);
        wsum += wraw[q];
        t.c[q] = (float)(K * s2 * x);
    }
    for (int q = 0; q < NQ; ++q) t.w[q] = (float)(wraw[q] / wsum);
    return t;
}

extern "C" void kernel_launch(void* const* d_in, const int* in_sizes, int n_in,
                              void* d_out, int out_size, void* d_ws, size_t ws_size,
                              hipStream_t stream) {
    (void)n_in; (void)d_ws; (void)ws_size; (void)out_size;
    const float* X = (const float*)d_in[0];
    float* out = (float*)d_out;
    int n = in_sizes[0] / 2;                  // 1,000,000

    static QTable T = make_table();           // host-side constants, same every call

    int n4 = (n % 4 == 0) ? (n / 4) : 0;      // float4 path needs 16B-aligned rows
    int rem = n - 4 * n4;
    int nthreads = n4 + rem;
    int grid = (nthreads + 255) / 256;

    adf_tanh_kernel<<<grid, 256, 0, stream>>>(X, out, n, n4, nthreads, T);
}

// Round 2
// 60.558 us; speedup vs baseline: 1.0089x; 1.0089x over previous
//
#include <hip/hip_runtime.h>
#include <cmath>

// ADF tanh moment propagation.
// Reference: 128-pt Gauss-Hermite. We use trapezoid quadrature on the
// Gaussian integral: h=0.5, nodes x=-3..3 (13 pts), weights ∝ exp(-x^2),
// normalized to sum 1.
//  - pole term (tanh/tanh^2 poles at Im z = pi/2): measured ~3.9e-3 absmax
//    at h=0.5 (dominates; scales ~e^{-2*pi*1.11/h}, so h must stay 0.5)
//  - truncation at |x|=3: <= erfc(3) ~= 2.2e-5 (integrand bounded by 1,
//    weights renormalized) — negligible.
// Threshold is 1.52e-2 absolute => ~4x margin, deterministic.

#define NQ 13

struct QTable {
    float c[NQ];  // K*sqrt(2)*x_q, where K = 2*log2(e); arg = fma(c, std, K*mu)
    float w[NQ];  // normalized weights, sum to 1
};

#if __has_builtin(__builtin_amdgcn_exp2f)
__device__ __forceinline__ float fast_exp2(float x) { return __builtin_amdgcn_exp2f(x); }
#else
__device__ __forceinline__ float fast_exp2(float x) { return exp2f(x); }
#endif
#if __has_builtin(__builtin_amdgcn_rcpf)
__device__ __forceinline__ float fast_rcp(float x) { return __builtin_amdgcn_rcpf(x); }
#else
__device__ __forceinline__ float fast_rcp(float x) { return 1.0f / x; }
#endif
#if __has_builtin(__builtin_amdgcn_sqrtf)
__device__ __forceinline__ float fast_sqrt(float x) { return __builtin_amdgcn_sqrtf(x); }
#else
__device__ __forceinline__ float fast_sqrt(float x) { return sqrtf(x); }
#endif

// kz = 2*log2(e)*z ; tanh(z) = 1 - 2/(exp2(kz)+1)
__device__ __forceinline__ float tanh_from_scaled(float kz) {
    float e = fast_exp2(kz);
    float r = fast_rcp(e + 1.0f);
    return fmaf(-2.0f, r, 1.0f);
}

__global__ __launch_bounds__(256) void adf_tanh_kernel(
    const float* __restrict__ X, float* __restrict__ out,
    int n, int n4, int nthreads, QTable T)
{
    constexpr float K = 2.8853900817779268f;  // 2/ln(2) = 2*log2(e)
    int i = blockIdx.x * 256 + threadIdx.x;

    if (i < n4) {
        // vectorized path: 4 elements per thread, rows are 16B-aligned (n%4==0)
        float4 mu4 = ((const float4*)X)[i];
        float4 vv4 = *((const float4*)(X + n) + i);
        float mu[4] = {mu4.x, mu4.y, mu4.z, mu4.w};
        float vv[4] = {vv4.x, vv4.y, vv4.z, vv4.w};
        float s[4], a0[4], m1[4], m2[4];
#pragma unroll
        for (int j = 0; j < 4; ++j) {
            s[j]  = fast_sqrt(vv[j]);
            a0[j] = K * mu[j];
            m1[j] = 0.0f;
            m2[j] = 0.0f;
        }
#pragma unroll
        for (int q = 0; q < NQ; ++q) {
            float c = T.c[q], w = T.w[q];
#pragma unroll
            for (int j = 0; j < 4; ++j) {
                float t = tanh_from_scaled(fmaf(c, s[j], a0[j]));
                m1[j] = fmaf(w, t, m1[j]);
                m2[j] = fmaf(w * t, t, m2[j]);
            }
        }
        float4 o1, o2;
        o1.x = m1[0]; o1.y = m1[1]; o1.z = m1[2]; o1.w = m1[3];
        o2.x = fmaf(-m1[0], m1[0], m2[0]);
        o2.y = fmaf(-m1[1], m1[1], m2[1]);
        o2.z = fmaf(-m1[2], m1[2], m2[2]);
        o2.w = fmaf(-m1[3], m1[3], m2[3]);
        ((float4*)out)[i] = o1;
        *((float4*)(out + n) + i) = o2;
    } else if (i < nthreads) {
        // scalar tail (n % 4 leftovers, or whole array if rows not 16B-aligned)
        int e = 4 * n4 + (i - n4);
        float mu = X[e];
        float vv = X[n + e];
        float s = fast_sqrt(vv);
        float a0 = K * mu;
        float m1 = 0.0f, m2 = 0.0f;
#pragma unroll
        for (int q = 0; q < NQ; ++q) {
            float t = tanh_from_scaled(fmaf(T.c[q], s, a0));
            m1 = fmaf(T.w[q], t, m1);
            m2 = fmaf(T.w[q] * t, t, m2);
        }
        out[e] = m1;
        out[n + e] = fmaf(-m1, m1, m2);
    }
}

static QTable make_table() {
    QTable t;
    const double h = 0.5;
    const double K = 2.0 / std::log(2.0);     // 2*log2(e)
    const double s2 = std::sqrt(2.0);
    double wraw[NQ];
    double wsum = 0.0;
    for (int q = 0; q < NQ; ++q) {
        double x = h * (double)(q - (NQ - 1) / 2);  // -3.0 .. 3.0
        wraw[q] = std::exp(-x * x);
        wsum += wraw[q];
        t.c[q] = (float)(K * s2 * x);
    }
    for (int q = 0; q < NQ; ++q) t.w[q] = (float)(wraw[q] / wsum);
    return t;
}

extern "C" void kernel_launch(void* const* d_in, const int* in_sizes, int n_in,
                              void* d_out, int out_size, void* d_ws, size_t ws_size,
                              hipStream_t stream) {
    (void)n_in; (void)d_ws; (void)ws_size; (void)out_size;
    const float* X = (const float*)d_in[0];
    float* out = (float*)d_out;
    int n = in_sizes[0] / 2;                  // 1,000,000

    static QTable T = make_table();           // host-side constants, same every call

    int n4 = (n % 4 == 0) ? (n / 4) : 0;      // float4 path needs 16B-aligned rows
    int rem = n - 4 * n4;
    int nthreads = n4 + rem;
    int grid = (nthreads + 255) / 256;

    adf_tanh_kernel<<<grid, 256, 0, stream>>>(X, out, n, n4, nthreads, T);
}